// Round 11
// baseline (367.575 us; speedup 1.0000x reference)
//
#include <hip/hip_runtime.h>
#include <hip/hip_bf16.h>
#include <stdint.h>

#define B_   8
#define N_   8192
#define C_   512
#define NB   256   // blocks per sequence (N_/32)
#define WIN  64

typedef __attribute__((ext_vector_type(8))) short short8;
typedef __attribute__((ext_vector_type(4))) float f32x4;
typedef __hip_bfloat16 bf16;

__device__ __forceinline__ void gload_lds16(const void* g, void* l) {
  __builtin_amdgcn_global_load_lds((const __attribute__((address_space(1))) void*)g,
                                   (__attribute__((address_space(3))) void*)l, 16, 0, 0);
}

__device__ __forceinline__ f32x4 mfma16(short8 a, short8 b, f32x4 c) {
  return __builtin_amdgcn_mfma_f32_16x16x32_bf16(a, b, c, 0, 0, 0);
}

// ---------------- weight conversion ----------------
// Coalesced LDS tile-transpose: W (512 x ldw f32, row-major) -> Wt[o][k] bf16.
// qkv=1 applies the head-interleave column permutation in 64-wide chunks.
__global__ __launch_bounds__(256) void k_conv_w(const float* __restrict__ W,
                                                const float* __restrict__ bsrc,
                                                bf16* __restrict__ Wt,
                                                float* __restrict__ bperm,
                                                int ldw, int qkv) {
  __shared__ float tile[32][65];
  const int cc = blockIdx.x, k0 = blockIdx.y * 32;
  const int src0 = cc * 64;
  const int o0 = qkv ? ((cc % 3) * 512 + (cc / 3) * 64) : src0;
  const int tid = threadIdx.x;
#pragma unroll
  for (int q = 0; q < 8; ++q) {
    int li = q * 256 + tid;
    int r = li >> 6, c = li & 63;
    tile[r][c] = W[(size_t)(k0 + r) * ldw + src0 + c];
  }
  __syncthreads();
#pragma unroll
  for (int q = 0; q < 8; ++q) {
    int li = q * 256 + tid;
    int c2 = li >> 5, kk = li & 31;
    Wt[(size_t)(o0 + c2) * 512 + k0 + kk] = __float2bfloat16(tile[kk][c2]);
  }
  if (qkv && blockIdx.y == 0 && tid < 64) bperm[o0 + tid] = bsrc[src0 + tid];
}

// ---------------- GEMM0 (fused x-conversion): C = f32(x) * Wt^T + bias --------
// 256x256 tile, BK=64, 8 waves (2M x 4N), dual 64KB buffers, ONE barrier/tile:
//   tile start: issue A f32 loads (8x dwordx4 -> regs) + B gload_lds (4) for t+1
//   compute tile t (24 ds_read_b128 + 64 MFMA, compiler lgkm-interleaved)
//   tail: cvt A->bf16 + 4x ds_write_b128 (XOR-swizzled slots; compiler auto-
//   waits the f32 regs), vmcnt(0) for B, lgkmcnt(0), barrier.
// Staging latency hides under own compute (r10's stage-after-barrier did not).
__global__ __launch_bounds__(512, 2) void k_gemm_x(const float* __restrict__ X,
                                                   const bf16* __restrict__ Bt,
                                                   const float* __restrict__ bias,
                                                   bf16* __restrict__ qb,
                                                   bf16* __restrict__ kb,
                                                   bf16* __restrict__ vb,
                                                   int NT) {
  extern __shared__ char gsm[];   // buf E at E*65536: A 32KB | B 32KB
  const int tid = threadIdx.x;
  const int lane = tid & 63, wid = tid >> 6;
  const int wr = wid >> 2, wcn = wid & 3;
  const int l15 = lane & 15, l4 = lane >> 4;

  const int nwg = gridDim.x;
  const int cpx = nwg >> 3;
  const int swz = (blockIdx.x & 7) * cpx + (blockIdx.x >> 3);
  const int mt = swz / NT, nt = swz % NT;
  const size_t m0 = (size_t)mt * 256;
  const int n0 = nt * 256;

  f32x4 acc[8][4];
#pragma unroll
  for (int fi = 0; fi < 8; ++fi)
#pragma unroll
    for (int fj = 0; fj < 4; ++fj) acc[fi][fj] = (f32x4){0.f, 0.f, 0.f, 0.f};

  float4 va[4][2];   // staged A f32 (32 VGPRs)

  // group G = q2*512+tid: row r=G>>3, K-group g=G&7 (8 bf16 = 8 f32 = 32B)
#define ISSUE_A(K0)                                                            \
  { _Pragma("unroll") for (int q2 = 0; q2 < 4; ++q2) {                         \
      int G = q2 * 512 + tid;                                                  \
      int r = G >> 3, g = G & 7;                                               \
      const float* p = X + (m0 + r) * 512 + (K0) + g * 8;                      \
      va[q2][0] = *(const float4*)p;                                           \
      va[q2][1] = *(const float4*)(p + 4);                                     \
    } }
#define WRITE_A(E)                                                             \
  { _Pragma("unroll") for (int q2 = 0; q2 < 4; ++q2) {                         \
      int G = q2 * 512 + tid;                                                  \
      int r = G >> 3, g = G & 7, slot = g ^ (r & 7);                           \
      union { bf16 b[8]; short8 s; } pk;                                       \
      _Pragma("unroll") for (int j = 0; j < 4; ++j) {                          \
        pk.b[j] = __float2bfloat16(va[q2][0][j]);                              \
        pk.b[4 + j] = __float2bfloat16(va[q2][1][j]);                          \
      }                                                                        \
      *(short8*)(gsm + (E) * 65536 + (r * 8 + slot) * 16) = pk.s;              \
    } }
#define ISSUE_B(E, K0)                                                         \
  { _Pragma("unroll") for (int q = 0; q < 4; ++q) {                            \
      int li = q * 512 + tid;                                                  \
      int r = li >> 3, g = (li & 7) ^ (r & 7);                                 \
      gload_lds16(Bt + (size_t)(n0 + r) * 512 + (K0) + g * 8,                  \
                  gsm + (E) * 65536 + 32768 + li * 16);                        \
    } }

  // prologue: tile 0
  ISSUE_A(0);
  __builtin_amdgcn_sched_barrier(0);
  ISSUE_B(0, 0);
  __builtin_amdgcn_sched_barrier(0);
  WRITE_A(0);
  asm volatile("s_waitcnt vmcnt(0)" ::: "memory");
  asm volatile("s_waitcnt lgkmcnt(0)" ::: "memory");
  __builtin_amdgcn_s_barrier();

  for (int t = 0; t < 8; ++t) {
    const int cur = t & 1, nxt = cur ^ 1;
    if (t < 7) {
      ISSUE_A((t + 1) * 64);
      __builtin_amdgcn_sched_barrier(0);
      ISSUE_B(nxt, (t + 1) * 64);
      __builtin_amdgcn_sched_barrier(0);
    }
    const char* Ab = gsm + cur * 65536;
    const char* Bb = Ab + 32768;

    short8 bf2[4][2], a0f[4][2], a1f[4][2];
#pragma unroll
    for (int f = 0; f < 4; ++f) {
      int rb = f * 64 + wcn * 16 + l15;
      const char* base = Bb + rb * 128;
      bf2[f][0] = *(const short8*)(base + ((l4 ^ (rb & 7)) << 4));
      bf2[f][1] = *(const short8*)(base + (((4 + l4) ^ (rb & 7)) << 4));
    }
#pragma unroll
    for (int f = 0; f < 4; ++f) {
      int ra = f * 32 + wr * 16 + l15;
      const char* base = Ab + ra * 128;
      a0f[f][0] = *(const short8*)(base + ((l4 ^ (ra & 7)) << 4));
      a0f[f][1] = *(const short8*)(base + (((4 + l4) ^ (ra & 7)) << 4));
    }
    __builtin_amdgcn_s_setprio(1);
#pragma unroll
    for (int f = 0; f < 4; ++f)
#pragma unroll
      for (int g = 0; g < 4; ++g) {
        acc[f][g] = mfma16(a0f[f][0], bf2[g][0], acc[f][g]);
        acc[f][g] = mfma16(a0f[f][1], bf2[g][1], acc[f][g]);
      }
    __builtin_amdgcn_s_setprio(0);
#pragma unroll
    for (int f = 0; f < 4; ++f) {
      int ra = 128 + f * 32 + wr * 16 + l15;
      const char* base = Ab + ra * 128;
      a1f[f][0] = *(const short8*)(base + ((l4 ^ (ra & 7)) << 4));
      a1f[f][1] = *(const short8*)(base + (((4 + l4) ^ (ra & 7)) << 4));
    }
    __builtin_amdgcn_s_setprio(1);
#pragma unroll
    for (int f = 0; f < 4; ++f)
#pragma unroll
      for (int g = 0; g < 4; ++g) {
        acc[4 + f][g] = mfma16(a1f[f][0], bf2[g][0], acc[4 + f][g]);
        acc[4 + f][g] = mfma16(a1f[f][1], bf2[g][1], acc[4 + f][g]);
      }
    __builtin_amdgcn_s_setprio(0);

    if (t < 7) {
      __builtin_amdgcn_sched_barrier(0);
      WRITE_A(nxt);                                     // auto-waits va vmcnt
      asm volatile("s_waitcnt vmcnt(0)" ::: "memory");  // B(t+1) landed
      asm volatile("s_waitcnt lgkmcnt(0)" ::: "memory");// writes+reads done
      __builtin_amdgcn_s_barrier();
      __builtin_amdgcn_sched_barrier(0);
    }
  }
#undef ISSUE_A
#undef WRITE_A
#undef ISSUE_B

  // epilogue: q,k,v contiguous [bs][blk][c]
#pragma unroll
  for (int fi = 0; fi < 8; ++fi)
#pragma unroll
    for (int fj = 0; fj < 4; ++fj) {
      int o = n0 + fj * 64 + wcn * 16 + l15;
      float bia = bias[o];
      int part = o >> 9;
      int c = o & 511;
      bf16* dst = part == 0 ? qb : (part == 1 ? kb : vb);
#pragma unroll
      for (int r = 0; r < 4; ++r) {
        size_t m = m0 + fi * 32 + wr * 16 + l4 * 4 + r;
        int bidx = (int)(m >> 13);
        int n = (int)(m & 8191);
        int blk = n >> 5, s = n & 31;
        size_t di = (((size_t)(bidx * 32 + s) * 256 + blk) << 9) | c;
        dst[di] = __float2bfloat16(acc[fi][fj][r] + bia);
      }
    }
}

// ---------------- GEMM1 (proj): same schedule, bf16 A via gload_lds ----------
__global__ __launch_bounds__(512, 2) void k_gemm(const bf16* __restrict__ A,
                                                 const bf16* __restrict__ Bt,
                                                 const float* __restrict__ bias,
                                                 float* __restrict__ outf,
                                                 int NT) {
  extern __shared__ char gsm[];   // buf E at E*65536: A 32KB | B 32KB
  const int tid = threadIdx.x;
  const int lane = tid & 63, wid = tid >> 6;
  const int wr = wid >> 2, wcn = wid & 3;
  const int l15 = lane & 15, l4 = lane >> 4;

  const int nwg = gridDim.x;
  const int cpx = nwg >> 3;
  const int swz = (blockIdx.x & 7) * cpx + (blockIdx.x >> 3);
  const int mt = swz / NT, nt = swz % NT;
  const size_t m0 = (size_t)mt * 256;
  const int n0 = nt * 256;

  f32x4 acc[8][4];
#pragma unroll
  for (int fi = 0; fi < 8; ++fi)
#pragma unroll
    for (int fj = 0; fj < 4; ++fj) acc[fi][fj] = (f32x4){0.f, 0.f, 0.f, 0.f};

#define STAGE(E, K0)                                                           \
  {                                                                            \
    _Pragma("unroll") for (int q = 0; q < 4; ++q) {                            \
      int li = q * 512 + tid;                                                  \
      int r = li >> 3, g = (li & 7) ^ (r & 7);                                 \
      gload_lds16(A + (m0 + r) * 512 + (K0) + g * 8,                           \
                  gsm + (E) * 65536 + li * 16);                                \
    }                                                                          \
    _Pragma("unroll") for (int q = 0; q < 4; ++q) {                            \
      int li = q * 512 + tid;                                                  \
      int r = li >> 3, g = (li & 7) ^ (r & 7);                                 \
      gload_lds16(Bt + (size_t)(n0 + r) * 512 + (K0) + g * 8,                  \
                  gsm + (E) * 65536 + 32768 + li * 16);                        \
    }                                                                          \
  }

  STAGE(0, 0);
  asm volatile("s_waitcnt vmcnt(0)" ::: "memory");
  __builtin_amdgcn_s_barrier();

  for (int t = 0; t < 8; ++t) {
    const int cur = t & 1, nxt = cur ^ 1;
    if (t < 7) {
      STAGE(nxt, (t + 1) * 64);
      __builtin_amdgcn_sched_barrier(0);
    }
    const char* Ab = gsm + cur * 65536;
    const char* Bb = Ab + 32768;

    short8 bf2[4][2], a0f[4][2], a1f[4][2];
#pragma unroll
    for (int f = 0; f < 4; ++f) {
      int rb = f * 64 + wcn * 16 + l15;
      const char* base = Bb + rb * 128;
      bf2[f][0] = *(const short8*)(base + ((l4 ^ (rb & 7)) << 4));
      bf2[f][1] = *(const short8*)(base + (((4 + l4) ^ (rb & 7)) << 4));
    }
#pragma unroll
    for (int f = 0; f < 4; ++f) {
      int ra = f * 32 + wr * 16 + l15;
      const char* base = Ab + ra * 128;
      a0f[f][0] = *(const short8*)(base + ((l4 ^ (ra & 7)) << 4));
      a0f[f][1] = *(const short8*)(base + (((4 + l4) ^ (ra & 7)) << 4));
    }
    __builtin_amdgcn_s_setprio(1);
#pragma unroll
    for (int f = 0; f < 4; ++f)
#pragma unroll
      for (int g = 0; g < 4; ++g) {
        acc[f][g] = mfma16(a0f[f][0], bf2[g][0], acc[f][g]);
        acc[f][g] = mfma16(a0f[f][1], bf2[g][1], acc[f][g]);
      }
    __builtin_amdgcn_s_setprio(0);
#pragma unroll
    for (int f = 0; f < 4; ++f) {
      int ra = 128 + f * 32 + wr * 16 + l15;
      const char* base = Ab + ra * 128;
      a1f[f][0] = *(const short8*)(base + ((l4 ^ (ra & 7)) << 4));
      a1f[f][1] = *(const short8*)(base + (((4 + l4) ^ (ra & 7)) << 4));
    }
    __builtin_amdgcn_s_setprio(1);
#pragma unroll
    for (int f = 0; f < 4; ++f)
#pragma unroll
      for (int g = 0; g < 4; ++g) {
        acc[4 + f][g] = mfma16(a1f[f][0], bf2[g][0], acc[4 + f][g]);
        acc[4 + f][g] = mfma16(a1f[f][1], bf2[g][1], acc[4 + f][g]);
      }
    __builtin_amdgcn_s_setprio(0);

    if (t < 7) {
      __builtin_amdgcn_sched_barrier(0);
      asm volatile("s_waitcnt vmcnt(0)" ::: "memory");   // tile t+1 landed
      asm volatile("s_waitcnt lgkmcnt(0)" ::: "memory"); // own reads done
      __builtin_amdgcn_s_barrier();
      __builtin_amdgcn_sched_barrier(0);
    }
  }
#undef STAGE

#pragma unroll
  for (int fi = 0; fi < 8; ++fi)
#pragma unroll
    for (int fj = 0; fj < 4; ++fj) {
      int o = n0 + fj * 64 + wcn * 16 + l15;
      float bia = bias[o];
#pragma unroll
      for (int r = 0; r < 4; ++r) {
        size_t m = m0 + fi * 32 + wr * 16 + l4 * 4 + r;
        outf[m * 512 + o] = acc[fi][fj][r] + bia;
      }
    }
}

// ---------------- v transpose: v[b][s][j][c] -> vT[b][s][c][j] ----------------
__global__ __launch_bounds__(256) void k_transpose_v(const bf16* __restrict__ v,
                                                     bf16* __restrict__ vT) {
  __shared__ bf16 t[32][36];
  int bs = blockIdx.x, j0 = blockIdx.y * 32, c0 = blockIdx.z * 32;
  const bf16* src = v + (size_t)bs * NB * C_;
  bf16* dst = vT + (size_t)bs * C_ * NB;
  int r = threadIdx.x >> 3, c4 = (threadIdx.x & 7) * 4;
  *(ushort4*)&t[r][c4] = *(const ushort4*)(src + (size_t)(j0 + r) * C_ + c0 + c4);
  __syncthreads();
  union { ushort4 u; bf16 b[4]; } o;
  o.b[0] = t[c4 + 0][r]; o.b[1] = t[c4 + 1][r];
  o.b[2] = t[c4 + 2][r]; o.b[3] = t[c4 + 3][r];
  *(ushort4*)(dst + (size_t)(c0 + r) * NB + j0 + c4) = o.u;
}

// ---------------- flash-style banded block attention (unchanged) -------------
#define QS_OFF   0
#define KB_OFF   32768
#define VB_OFF   98304
#define SS_OFF   131072
#define PS_OFF   135296
#define SR_OFF   137856
#define MR_OFF   141952
#define LR_OFF   142080
#define AL_OFF   142208
#define ATTN_LDS 142336

__global__ __launch_bounds__(512) void k_attn(const bf16* __restrict__ qg,
                                              const bf16* __restrict__ kg,
                                              const bf16* __restrict__ vTg,
                                              bf16* __restrict__ outb) {
  extern __shared__ char smc[];
  float* Ssf  = (float*)(smc + SS_OFF);
  bf16*  Psb  = (bf16*)(smc + PS_OFF);
  float* Sred = (float*)(smc + SR_OFF);
  float* mrow = (float*)(smc + MR_OFF);
  float* lrow = (float*)(smc + LR_OFF);
  float* alph = (float*)(smc + AL_OFF);

  const int tid = threadIdx.x, lane = tid & 63, wid = tid >> 6;
  const int l15 = lane & 15, l4 = lane >> 4;
  const int gt = (blockIdx.x & 7) * 256 + (blockIdx.x >> 3);
  const int bs = gt >> 3;
  const int b = bs >> 5, s = bs & 31;
  const int i0 = (gt & 7) * 32;
  const int jlo = max(0, i0 - WIN);
  const int jhi = min(NB - 1, i0 + 31 + WIN);
  const int nch = (jhi - jlo + 1) >> 5;        // 3..5, band always 32-aligned
  const bf16* Qb = qg + (size_t)bs * NB * C_;
  const bf16* Kb = kg + (size_t)bs * NB * C_;
  const bf16* Vb = vTg + (size_t)bs * C_ * NB;

  // roles
  const int qh_qk = (wid >> 2) & 1, jh = (wid >> 1) & 1, ks = wid & 1;
  const int qh_pv = wid >> 2, cq = wid & 3;

  f32x4 O[8];
#pragma unroll
  for (int f = 0; f < 8; ++f) O[f] = (f32x4){0.f, 0.f, 0.f, 0.f};

  if (tid < 32) { mrow[tid] = -1e30f; lrow[tid] = 0.f; }

  // stage Q (32 rows x 1KB, swizzled source cols) + K chunk 0
#pragma unroll
  for (int q = 0; q < 4; ++q) {
    int li = q * 512 + tid;
    int row = li >> 6, g = (li & 63) ^ (row & 15);
    gload_lds16(Qb + (size_t)(i0 + row) * C_ + g * 8, smc + QS_OFF + li * 16);
  }
#pragma unroll
  for (int q = 0; q < 4; ++q) {
    int li = q * 512 + tid;
    int row = li >> 6, g = (li & 63) ^ (row & 15);
    gload_lds16(Kb + (size_t)(jlo + row) * C_ + g * 8, smc + KB_OFF + li * 16);
  }

  for (int t = 0; t < nch; ++t) {
    const int j0 = jlo + t * 32;
    asm volatile("s_waitcnt vmcnt(0) lgkmcnt(0)" ::: "memory");
    __builtin_amdgcn_s_barrier();
    __builtin_amdgcn_sched_barrier(0);

    // issue V(t) then (optionally) K(t+1): 4+4 instr/thread
#pragma unroll
    for (int q = 0; q < 4; ++q) {
      int li = q * 512 + tid;
      int c = li >> 2, g = (li & 3) ^ (c & 3);
      gload_lds16(Vb + (size_t)c * NB + j0 + g * 8, smc + VB_OFF + li * 16);
    }
    if (t + 1 < nch) {
      int jn = j0 + 32;
      char* kdst = smc + KB_OFF + ((t + 1) & 1) * 32768;
#pragma unroll
      for (int q = 0; q < 4; ++q) {
        int li = q * 512 + tid;
        int row = li >> 6, g = (li & 63) ^ (row & 15);
        gload_lds16(Kb + (size_t)(jn + row) * C_ + g * 8, kdst + li * 16);
      }
    }

    // QK^T(t): S[32i x 32j], K-dim split 2-way across wave pairs
    {
      const int arow = qh_qk * 16 + l15;
      const int brow = jh * 16 + l15;
      const char* Qbase = smc + QS_OFF + arow * 1024;
      const char* Kbase = smc + KB_OFF + (t & 1) * 32768 + brow * 1024;
      f32x4 a0 = (f32x4){0.f, 0.f, 0.f, 0.f}, a1 = a0;
      __builtin_amdgcn_s_setprio(1);
#pragma unroll
      for (int cc = 0; cc < 8; ++cc) {
        int sa = (ks * 32 + cc * 4 + l4) ^ (arow & 15);
        int sb = (ks * 32 + cc * 4 + l4) ^ (brow & 15);
        short8 av = *(const short8*)(Qbase + sa * 16);
        short8 bv = *(const short8*)(Kbase + sb * 16);
        if (cc & 1) a1 = mfma16(av, bv, a1);
        else        a0 = mfma16(av, bv, a0);
      }
      __builtin_amdgcn_s_setprio(0);
      f32x4 acc = a0 + a1;
      if (ks) {
        *(f32x4*)&Sred[(wid >> 1) * 256 + lane * 4] = acc;
      }
      asm volatile("s_waitcnt lgkmcnt(0)" ::: "memory");
      __builtin_amdgcn_s_barrier();
      __builtin_amdgcn_sched_barrier(0);
      if (!ks) {
        f32x4 su = acc + *(f32x4*)&Sred[(wid >> 1) * 256 + lane * 4];
        int jg = j0 + jh * 16 + l15;
#pragma unroll
        for (int r = 0; r < 4; ++r) {
          int i_in = qh_qk * 16 + l4 * 4 + r;
          int i_abs = i0 + i_in;
          bool valid = (jg >= i_abs - WIN) && (jg <= i_abs + WIN);
          Ssf[i_in * 33 + jh * 16 + l15] = valid ? su[r] * 0.125f : -1e30f;
        }
      }
      asm volatile("s_waitcnt lgkmcnt(0)" ::: "memory");
      __builtin_amdgcn_s_barrier();
      __builtin_amdgcn_sched_barrier(0);
    }

    // online softmax: 16 threads per row
    {
      int row = tid >> 4, u = tid & 15;
      float s0 = Ssf[row * 33 + u], s1 = Ssf[row * 33 + u + 16];
      float mc = fmaxf(s0, s1);
      mc = fmaxf(mc, __shfl_xor(mc, 1));
      mc = fmaxf(mc, __shfl_xor(mc, 2));
      mc = fmaxf(mc, __shfl_xor(mc, 4));
      mc = fmaxf(mc, __shfl_xor(mc, 8));
      float mo = mrow[row];
      float mn = fmaxf(mo, mc);
      float a = __expf(mo - mn);
      float p0 = __expf(s0 - mn), p1 = __expf(s1 - mn);
      float ps = p0 + p1;
      ps += __shfl_xor(ps, 1);
      ps += __shfl_xor(ps, 2);
      ps += __shfl_xor(ps, 4);
      ps += __shfl_xor(ps, 8);
      if (u == 0) {
        lrow[row] = lrow[row] * a + ps;
        mrow[row] = mn;
        alph[row] = a;
      }
      Psb[row * 40 + u] = __float2bfloat16(p0);
      Psb[row * 40 + u + 16] = __float2bfloat16(p1);
    }
    if (t + 1 < nch)
      asm volatile("s_waitcnt vmcnt(4) lgkmcnt(0)" ::: "memory");
    else
      asm volatile("s_waitcnt vmcnt(0) lgkmcnt(0)" ::: "memory");
    __builtin_amdgcn_s_barrier();
    __builtin_amdgcn_sched_barrier(0);

    // PV(t): O[i16 x c16] += P * V^T, alpha-rescale first
    {
      float ar[4];
#pragma unroll
      for (int r = 0; r < 4; ++r) ar[r] = alph[qh_pv * 16 + l4 * 4 + r];
      short8 pa = *(const short8*)(smc + PS_OFF + (qh_pv * 16 + l15) * 80 + l4 * 16);
      __builtin_amdgcn_s_setprio(1);
#pragma unroll
      for (int f = 0; f < 8; ++f) {
        int c = cq * 128 + f * 16 + l15;
        short8 vv = *(const short8*)(smc + VB_OFF + c * 64 + ((l4 ^ (c & 3)) << 4));
#pragma unroll
        for (int r = 0; r < 4; ++r) O[f][r] *= ar[r];
        O[f] = mfma16(pa, vv, O[f]);
      }
      __builtin_amdgcn_s_setprio(0);
    }
    __builtin_amdgcn_sched_barrier(0);
  }

  // epilogue: normalize and store
  asm volatile("s_waitcnt lgkmcnt(0)" ::: "memory");
  __builtin_amdgcn_s_barrier();
  {
    float lr[4];
#pragma unroll
    for (int r = 0; r < 4; ++r) lr[r] = 1.f / lrow[qh_pv * 16 + l4 * 4 + r];
#pragma unroll
    for (int f = 0; f < 8; ++f) {
      int c = cq * 128 + f * 16 + l15;
#pragma unroll
      for (int r = 0; r < 4; ++r) {
        int il = qh_pv * 16 + l4 * 4 + r;
        int n = (i0 + il) * 32 + s;
        outb[((size_t)b * N_ + n) * C_ + c] = __float2bfloat16(O[f][r] * lr[r]);
      }
    }
  }
}

// ---------------- launch ----------------
extern "C" void kernel_launch(void* const* d_in, const int* in_sizes, int n_in,
                              void* d_out, int out_size, void* d_ws, size_t ws_size,
                              hipStream_t stream) {
  const float* x = (const float*)d_in[0];
  const float* Wqkv = (const float*)d_in[1];
  const float* bqkv = (const float*)d_in[2];
  const float* Wproj = (const float*)d_in[3];
  const float* bproj = (const float*)d_in[4];

  char* ws = (char*)d_ws;
  const size_t SLOT = 67108864ull;           // 64 MiB (33.5M bf16)
  bf16* slotA = (bf16*)ws;                   // vT
  bf16* slotB = (bf16*)(ws + SLOT);          // v, then attn_out
  bf16* Wqkv_t = (bf16*)(ws + 2 * SLOT);
  bf16* Wproj_t = (bf16*)(ws + 2 * SLOT + 1572864);
  float* bias_perm = (float*)(ws + 2 * SLOT + 1572864 + 524288);
  bf16* qbuf = (bf16*)d_out;                 // q,k scratch inside d_out (dead before proj writes)
  bf16* kbuf = qbuf + 33554432ull;

  static int attr_done = 0;
  if (!attr_done) {
    hipFuncSetAttribute((const void*)k_gemm_x,
                        hipFuncAttributeMaxDynamicSharedMemorySize, 131072);
    hipFuncSetAttribute((const void*)k_gemm,
                        hipFuncAttributeMaxDynamicSharedMemorySize, 131072);
    hipFuncSetAttribute((const void*)k_attn,
                        hipFuncAttributeMaxDynamicSharedMemorySize, ATTN_LDS);
    attr_done = 1;
  }

  k_conv_w<<<dim3(24, 16), 256, 0, stream>>>(Wqkv, bqkv, Wqkv_t, bias_perm, 1536, 1);
  k_conv_w<<<dim3(8, 16), 256, 0, stream>>>(Wproj, nullptr, Wproj_t, nullptr, 512, 0);

  // qkv projection (fused x-conversion): A=x f32 -> q,k (d_out), v (slotB)
  k_gemm_x<<<1536, 512, 131072, stream>>>(x, Wqkv_t, bias_perm,
                                          qbuf, kbuf, slotB, 6);
  // v -> vT (slotA)
  k_transpose_v<<<dim3(256, 8, 16), 256, 0, stream>>>(slotB, slotA);
  // attention -> attn_out (slotB; v dead)
  k_attn<<<2048, 512, ATTN_LDS, stream>>>(qbuf, kbuf, slotA, slotB);
  // proj: A=attn_out (slotB), Bt=Wproj_t -> d_out f32 (q,k dead)
  k_gemm<<<512, 512, 131072, stream>>>(slotB, Wproj_t, bproj, (float*)d_out, 2);
}

// Round 12
// 328.999 us; speedup vs baseline: 1.1173x; 1.1173x over previous
//
#include <hip/hip_runtime.h>
#include <hip/hip_bf16.h>
#include <stdint.h>

#define B_   8
#define N_   8192
#define C_   512
#define NB   256   // blocks per sequence (N_/32)
#define WIN  64

typedef __attribute__((ext_vector_type(8))) short short8;
typedef __attribute__((ext_vector_type(4))) float f32x4;
typedef __hip_bfloat16 bf16;

__device__ __forceinline__ void gload_lds16(const void* g, void* l) {
  __builtin_amdgcn_global_load_lds((const __attribute__((address_space(1))) void*)g,
                                   (__attribute__((address_space(3))) void*)l, 16, 0, 0);
}

__device__ __forceinline__ f32x4 mfma16(short8 a, short8 b, f32x4 c) {
  return __builtin_amdgcn_mfma_f32_16x16x32_bf16(a, b, c, 0, 0, 0);
}

// ---------------- conversion kernels ----------------

__global__ __launch_bounds__(256) void k_conv_x(const float4* __restrict__ x,
                                                ushort4* __restrict__ xb) {
  size_t idx = (size_t)blockIdx.x * 256 + threadIdx.x;   // one float4 each
  float4 v = x[idx];
  union { ushort4 u; bf16 b[4]; } o;
  o.b[0] = __float2bfloat16(v.x); o.b[1] = __float2bfloat16(v.y);
  o.b[2] = __float2bfloat16(v.z); o.b[3] = __float2bfloat16(v.w);
  xb[idx] = o.u;
}

// Coalesced LDS tile-transpose: W (512 x ldw f32, row-major) -> Wt[o][k] bf16.
// qkv=1 applies the head-interleave column permutation in 64-wide chunks.
__global__ __launch_bounds__(256) void k_conv_w(const float* __restrict__ W,
                                                const float* __restrict__ bsrc,
                                                bf16* __restrict__ Wt,
                                                float* __restrict__ bperm,
                                                int ldw, int qkv) {
  __shared__ float tile[32][65];
  const int cc = blockIdx.x, k0 = blockIdx.y * 32;
  const int src0 = cc * 64;
  const int o0 = qkv ? ((cc % 3) * 512 + (cc / 3) * 64) : src0;
  const int tid = threadIdx.x;
#pragma unroll
  for (int q = 0; q < 8; ++q) {
    int li = q * 256 + tid;
    int r = li >> 6, c = li & 63;
    tile[r][c] = W[(size_t)(k0 + r) * ldw + src0 + c];
  }
  __syncthreads();
#pragma unroll
  for (int q = 0; q < 8; ++q) {
    int li = q * 256 + tid;
    int c2 = li >> 5, kk = li & 31;
    Wt[(size_t)(o0 + c2) * 512 + k0 + kk] = __float2bfloat16(tile[kk][c2]);
  }
  if (qkv && blockIdx.y == 0 && tid < 64) bperm[o0 + tid] = bsrc[src0 + tid];
}

// ---------------- GEMM: 256x256 tile, BK=64, 8-phase schedule (r6, proven) ----
// 8 waves (2M x 4N); frag fi at row fi*32+wr*16, fj at col fj*64+wcn*16 so
// quadrant (fih,fjh) reads exactly A-half(fih) + B-half(fjh) (each 128x64).
// LDS 128KB: buf d (d=t&1): A-half h at d*65536+h*16384, B-half h at +32768.
// Per K-tile: 4 phases (A0B0, A0B1, A1B0, A1B1), 16 MFMA each; one half-tile
// of tile t+1 staged per phase (order A0,B0,B1,A1); counted vmcnt(4) at phase
// ends 1,2,4, never 0 mid-loop. T2 slot-XOR swizzle (measured 0 conflicts).
#define WAITV(N) asm volatile("s_waitcnt vmcnt(" #N ")" ::: "memory")

template <int EPI>
__global__ __launch_bounds__(512, 2) void k_gemm(const bf16* __restrict__ A,
                                                 const bf16* __restrict__ Bt,
                                                 const float* __restrict__ bias,
                                                 bf16* __restrict__ qb,
                                                 bf16* __restrict__ kb,
                                                 bf16* __restrict__ vb,
                                                 float* __restrict__ outf,
                                                 int NT) {
  extern __shared__ char gsm[];
  const int tid = threadIdx.x;
  const int lane = tid & 63, wid = tid >> 6;
  const int wr = wid >> 2, wcn = wid & 3;
  const int l15 = lane & 15, l4 = lane >> 4;
  const int sx = l15 & 7;

  const int nwg = gridDim.x;
  const int cpx = nwg >> 3;
  const int swz = (blockIdx.x & 7) * cpx + (blockIdx.x >> 3);
  const int mt = swz / NT, nt = swz % NT;
  const size_t m0 = (size_t)mt * 256;
  const int n0 = nt * 256;

  f32x4 acc[8][4];
#pragma unroll
  for (int fi = 0; fi < 8; ++fi)
#pragma unroll
    for (int fj = 0; fj < 4; ++fj) acc[fi][fj] = (f32x4){0.f, 0.f, 0.f, 0.f};

#define STAGE_A(E, H, K0)                                                      \
  { _Pragma("unroll") for (int q = 0; q < 2; ++q) {                            \
      int li = q * 512 + tid;                                                  \
      int r = li >> 3, g = (li & 7) ^ (r & 7);                                 \
      gload_lds16(A + (m0 + (H) * 128 + r) * 512 + (K0) + g * 8,               \
                  gsm + (E) * 65536 + (H) * 16384 + li * 16);                  \
    } }
#define STAGE_B(E, H, K0)                                                      \
  { _Pragma("unroll") for (int q = 0; q < 2; ++q) {                            \
      int li = q * 512 + tid;                                                  \
      int r = li >> 3, g = (li & 7) ^ (r & 7);                                 \
      gload_lds16(Bt + (size_t)(n0 + (H) * 128 + r) * 512 + (K0) + g * 8,      \
                  gsm + (E) * 65536 + 32768 + (H) * 16384 + li * 16);          \
    } }

#define PHASE(FIH, FJH, LOADA, STAGE_STMT, WAIT_STMT)                          \
  {                                                                            \
    const char* Ab = gsm + d * 65536 + (FIH) * 16384;                          \
    const char* Bb = gsm + d * 65536 + 32768 + (FJH) * 16384;                  \
    if (LOADA) {                                                               \
      _Pragma("unroll") for (int f = 0; f < 4; ++f) {                          \
        int rA = f * 32 + wr * 16 + l15;                                       \
        af[f][0] = *(const short8*)(Ab + rA * 128 + ((l4 ^ sx) << 4));         \
        af[f][1] = *(const short8*)(Ab + rA * 128 + (((4 + l4) ^ sx) << 4));   \
      }                                                                        \
    }                                                                          \
    _Pragma("unroll") for (int f = 0; f < 2; ++f) {                            \
      int rB = f * 64 + wcn * 16 + l15;                                        \
      bfr[f][0] = *(const short8*)(Bb + rB * 128 + ((l4 ^ sx) << 4));          \
      bfr[f][1] = *(const short8*)(Bb + rB * 128 + (((4 + l4) ^ sx) << 4));    \
    }                                                                          \
    STAGE_STMT;                                                                \
    __builtin_amdgcn_sched_barrier(0);                                         \
    __builtin_amdgcn_s_barrier();                                              \
    __builtin_amdgcn_sched_barrier(0);                                         \
    __builtin_amdgcn_s_setprio(1);                                             \
    _Pragma("unroll") for (int f = 0; f < 4; ++f)                              \
      _Pragma("unroll") for (int g = 0; g < 2; ++g) {                          \
        acc[(FIH) * 4 + f][(FJH) * 2 + g] =                                    \
            mfma16(af[f][0], bfr[g][0], acc[(FIH) * 4 + f][(FJH) * 2 + g]);    \
        acc[(FIH) * 4 + f][(FJH) * 2 + g] =                                    \
            mfma16(af[f][1], bfr[g][1], acc[(FIH) * 4 + f][(FJH) * 2 + g]);    \
      }                                                                        \
    __builtin_amdgcn_s_setprio(0);                                             \
    __builtin_amdgcn_sched_barrier(0);                                         \
    WAIT_STMT;                                                                 \
    __builtin_amdgcn_s_barrier();                                              \
  }

  // prologue: tile 0 (order A0,B0,B1,A1); vmcnt(4) -> A0,B0 landed
  STAGE_A(0, 0, 0); STAGE_B(0, 0, 0); STAGE_B(0, 1, 0); STAGE_A(0, 1, 0);
  WAITV(4);
  __builtin_amdgcn_s_barrier();

  short8 af[4][2], bfr[2][2];
  for (int t = 0; t < 8; ++t) {
    const int d = t & 1, e = d ^ 1;
    const int kn = (t + 1) * 64;
    PHASE(0, 0, 1,
          { if (t < 7) STAGE_A(e, 0, kn); },
          { if (t < 7) { WAITV(4); } else { WAITV(2); } });
    PHASE(0, 1, 0,
          { if (t < 7) STAGE_B(e, 0, kn); },
          { if (t < 7) { WAITV(4); } else { WAITV(0); } });
    PHASE(1, 0, 1,
          { if (t < 7) STAGE_B(e, 1, kn); },
          { });
    PHASE(1, 1, 0,
          { if (t < 7) STAGE_A(e, 1, kn); },
          { if (t < 7) { WAITV(4); } });
  }
#undef PHASE
#undef STAGE_A
#undef STAGE_B

  if (EPI == 0) {
#pragma unroll
    for (int fi = 0; fi < 8; ++fi)
#pragma unroll
      for (int fj = 0; fj < 4; ++fj) {
        int o = n0 + fj * 64 + wcn * 16 + l15;
        float bia = bias[o];
        int part = o >> 9;
        int c = o & 511;
        bf16* dst = part == 0 ? qb : (part == 1 ? kb : vb);
#pragma unroll
        for (int r = 0; r < 4; ++r) {
          size_t m = m0 + fi * 32 + wr * 16 + l4 * 4 + r;
          int bidx = (int)(m >> 13);
          int n = (int)(m & 8191);
          int blk = n >> 5, s = n & 31;
          size_t di = (((size_t)(bidx * 32 + s) * 256 + blk) << 9) | c;
          dst[di] = __float2bfloat16(acc[fi][fj][r] + bia);
        }
      }
  } else {
#pragma unroll
    for (int fi = 0; fi < 8; ++fi)
#pragma unroll
      for (int fj = 0; fj < 4; ++fj) {
        int o = n0 + fj * 64 + wcn * 16 + l15;
        float bia = bias[o];
#pragma unroll
        for (int r = 0; r < 4; ++r) {
          size_t m = m0 + fi * 32 + wr * 16 + l4 * 4 + r;
          outf[m * 512 + o] = acc[fi][fj][r] + bia;
        }
      }
  }
}

// ---------------- v transpose: v[b][s][j][c] -> vT[b][s][c][j] ----------------
__global__ __launch_bounds__(256) void k_transpose_v(const bf16* __restrict__ v,
                                                     bf16* __restrict__ vT) {
  __shared__ bf16 t[32][36];
  int bs = blockIdx.x, j0 = blockIdx.y * 32, c0 = blockIdx.z * 32;
  const bf16* src = v + (size_t)bs * NB * C_;
  bf16* dst = vT + (size_t)bs * C_ * NB;
  int r = threadIdx.x >> 3, c4 = (threadIdx.x & 7) * 4;
  *(ushort4*)&t[r][c4] = *(const ushort4*)(src + (size_t)(j0 + r) * C_ + c0 + c4);
  __syncthreads();
  union { ushort4 u; bf16 b[4]; } o;
  o.b[0] = t[c4 + 0][r]; o.b[1] = t[c4 + 1][r];
  o.b[2] = t[c4 + 2][r]; o.b[3] = t[c4 + 3][r];
  *(ushort4*)(dst + (size_t)(c0 + r) * NB + j0 + c4) = o.u;
}

// ---------------- flash-style banded block attention (proven r4) -------------
#define QS_OFF   0
#define KB_OFF   32768
#define VB_OFF   98304
#define SS_OFF   131072
#define PS_OFF   135296
#define SR_OFF   137856
#define MR_OFF   141952
#define LR_OFF   142080
#define AL_OFF   142208
#define ATTN_LDS 142336

__global__ __launch_bounds__(512) void k_attn(const bf16* __restrict__ qg,
                                              const bf16* __restrict__ kg,
                                              const bf16* __restrict__ vTg,
                                              bf16* __restrict__ outb) {
  extern __shared__ char smc[];
  float* Ssf  = (float*)(smc + SS_OFF);
  bf16*  Psb  = (bf16*)(smc + PS_OFF);
  float* Sred = (float*)(smc + SR_OFF);
  float* mrow = (float*)(smc + MR_OFF);
  float* lrow = (float*)(smc + LR_OFF);
  float* alph = (float*)(smc + AL_OFF);

  const int tid = threadIdx.x, lane = tid & 63, wid = tid >> 6;
  const int l15 = lane & 15, l4 = lane >> 4;
  const int gt = (blockIdx.x & 7) * 256 + (blockIdx.x >> 3);
  const int bs = gt >> 3;
  const int b = bs >> 5, s = bs & 31;
  const int i0 = (gt & 7) * 32;
  const int jlo = max(0, i0 - WIN);
  const int jhi = min(NB - 1, i0 + 31 + WIN);
  const int nch = (jhi - jlo + 1) >> 5;        // 3..5, band always 32-aligned
  const bf16* Qb = qg + (size_t)bs * NB * C_;
  const bf16* Kb = kg + (size_t)bs * NB * C_;
  const bf16* Vb = vTg + (size_t)bs * C_ * NB;

  const int qh_qk = (wid >> 2) & 1, jh = (wid >> 1) & 1, ks = wid & 1;
  const int qh_pv = wid >> 2, cq = wid & 3;

  f32x4 O[8];
#pragma unroll
  for (int f = 0; f < 8; ++f) O[f] = (f32x4){0.f, 0.f, 0.f, 0.f};

  if (tid < 32) { mrow[tid] = -1e30f; lrow[tid] = 0.f; }

#pragma unroll
  for (int q = 0; q < 4; ++q) {
    int li = q * 512 + tid;
    int row = li >> 6, g = (li & 63) ^ (row & 15);
    gload_lds16(Qb + (size_t)(i0 + row) * C_ + g * 8, smc + QS_OFF + li * 16);
  }
#pragma unroll
  for (int q = 0; q < 4; ++q) {
    int li = q * 512 + tid;
    int row = li >> 6, g = (li & 63) ^ (row & 15);
    gload_lds16(Kb + (size_t)(jlo + row) * C_ + g * 8, smc + KB_OFF + li * 16);
  }

  for (int t = 0; t < nch; ++t) {
    const int j0 = jlo + t * 32;
    asm volatile("s_waitcnt vmcnt(0) lgkmcnt(0)" ::: "memory");
    __builtin_amdgcn_s_barrier();
    __builtin_amdgcn_sched_barrier(0);

#pragma unroll
    for (int q = 0; q < 4; ++q) {
      int li = q * 512 + tid;
      int c = li >> 2, g = (li & 3) ^ (c & 3);
      gload_lds16(Vb + (size_t)c * NB + j0 + g * 8, smc + VB_OFF + li * 16);
    }
    if (t + 1 < nch) {
      int jn = j0 + 32;
      char* kdst = smc + KB_OFF + ((t + 1) & 1) * 32768;
#pragma unroll
      for (int q = 0; q < 4; ++q) {
        int li = q * 512 + tid;
        int row = li >> 6, g = (li & 63) ^ (row & 15);
        gload_lds16(Kb + (size_t)(jn + row) * C_ + g * 8, kdst + li * 16);
      }
    }

    {
      const int arow = qh_qk * 16 + l15;
      const int brow = jh * 16 + l15;
      const char* Qbase = smc + QS_OFF + arow * 1024;
      const char* Kbase = smc + KB_OFF + (t & 1) * 32768 + brow * 1024;
      f32x4 a0 = (f32x4){0.f, 0.f, 0.f, 0.f}, a1 = a0;
      __builtin_amdgcn_s_setprio(1);
#pragma unroll
      for (int cc = 0; cc < 8; ++cc) {
        int sa = (ks * 32 + cc * 4 + l4) ^ (arow & 15);
        int sb = (ks * 32 + cc * 4 + l4) ^ (brow & 15);
        short8 av = *(const short8*)(Qbase + sa * 16);
        short8 bv = *(const short8*)(Kbase + sb * 16);
        if (cc & 1) a1 = mfma16(av, bv, a1);
        else        a0 = mfma16(av, bv, a0);
      }
      __builtin_amdgcn_s_setprio(0);
      f32x4 acc = a0 + a1;
      if (ks) {
        *(f32x4*)&Sred[(wid >> 1) * 256 + lane * 4] = acc;
      }
      asm volatile("s_waitcnt lgkmcnt(0)" ::: "memory");
      __builtin_amdgcn_s_barrier();
      __builtin_amdgcn_sched_barrier(0);
      if (!ks) {
        f32x4 su = acc + *(f32x4*)&Sred[(wid >> 1) * 256 + lane * 4];
        int jg = j0 + jh * 16 + l15;
#pragma unroll
        for (int r = 0; r < 4; ++r) {
          int i_in = qh_qk * 16 + l4 * 4 + r;
          int i_abs = i0 + i_in;
          bool valid = (jg >= i_abs - WIN) && (jg <= i_abs + WIN);
          Ssf[i_in * 33 + jh * 16 + l15] = valid ? su[r] * 0.125f : -1e30f;
        }
      }
      asm volatile("s_waitcnt lgkmcnt(0)" ::: "memory");
      __builtin_amdgcn_s_barrier();
      __builtin_amdgcn_sched_barrier(0);
    }

    {
      int row = tid >> 4, u = tid & 15;
      float s0 = Ssf[row * 33 + u], s1 = Ssf[row * 33 + u + 16];
      float mc = fmaxf(s0, s1);
      mc = fmaxf(mc, __shfl_xor(mc, 1));
      mc = fmaxf(mc, __shfl_xor(mc, 2));
      mc = fmaxf(mc, __shfl_xor(mc, 4));
      mc = fmaxf(mc, __shfl_xor(mc, 8));
      float mo = mrow[row];
      float mn = fmaxf(mo, mc);
      float a = __expf(mo - mn);
      float p0 = __expf(s0 - mn), p1 = __expf(s1 - mn);
      float ps = p0 + p1;
      ps += __shfl_xor(ps, 1);
      ps += __shfl_xor(ps, 2);
      ps += __shfl_xor(ps, 4);
      ps += __shfl_xor(ps, 8);
      if (u == 0) {
        lrow[row] = lrow[row] * a + ps;
        mrow[row] = mn;
        alph[row] = a;
      }
      Psb[row * 40 + u] = __float2bfloat16(p0);
      Psb[row * 40 + u + 16] = __float2bfloat16(p1);
    }
    if (t + 1 < nch)
      asm volatile("s_waitcnt vmcnt(4) lgkmcnt(0)" ::: "memory");
    else
      asm volatile("s_waitcnt vmcnt(0) lgkmcnt(0)" ::: "memory");
    __builtin_amdgcn_s_barrier();
    __builtin_amdgcn_sched_barrier(0);

    {
      float ar[4];
#pragma unroll
      for (int r = 0; r < 4; ++r) ar[r] = alph[qh_pv * 16 + l4 * 4 + r];
      short8 pa = *(const short8*)(smc + PS_OFF + (qh_pv * 16 + l15) * 80 + l4 * 16);
      __builtin_amdgcn_s_setprio(1);
#pragma unroll
      for (int f = 0; f < 8; ++f) {
        int c = cq * 128 + f * 16 + l15;
        short8 vv = *(const short8*)(smc + VB_OFF + c * 64 + ((l4 ^ (c & 3)) << 4));
#pragma unroll
        for (int r = 0; r < 4; ++r) O[f][r] *= ar[r];
        O[f] = mfma16(pa, vv, O[f]);
      }
      __builtin_amdgcn_s_setprio(0);
    }
    __builtin_amdgcn_sched_barrier(0);
  }

  asm volatile("s_waitcnt lgkmcnt(0)" ::: "memory");
  __builtin_amdgcn_s_barrier();
  {
    float lr[4];
#pragma unroll
    for (int r = 0; r < 4; ++r) lr[r] = 1.f / lrow[qh_pv * 16 + l4 * 4 + r];
#pragma unroll
    for (int f = 0; f < 8; ++f) {
      int c = cq * 128 + f * 16 + l15;
#pragma unroll
      for (int r = 0; r < 4; ++r) {
        int il = qh_pv * 16 + l4 * 4 + r;
        int n = (i0 + il) * 32 + s;
        outb[((size_t)b * N_ + n) * C_ + c] = __float2bfloat16(O[f][r] * lr[r]);
      }
    }
  }
}

// ---------------- launch ----------------
extern "C" void kernel_launch(void* const* d_in, const int* in_sizes, int n_in,
                              void* d_out, int out_size, void* d_ws, size_t ws_size,
                              hipStream_t stream) {
  const float* x = (const float*)d_in[0];
  const float* Wqkv = (const float*)d_in[1];
  const float* bqkv = (const float*)d_in[2];
  const float* Wproj = (const float*)d_in[3];
  const float* bproj = (const float*)d_in[4];

  char* ws = (char*)d_ws;
  const size_t SLOT = 67108864ull;           // 64 MiB (33.5M bf16)
  bf16* slotA = (bf16*)ws;                   // xb, then vT
  bf16* slotB = (bf16*)(ws + SLOT);          // v, then attn_out
  bf16* Wqkv_t = (bf16*)(ws + 2 * SLOT);
  bf16* Wproj_t = (bf16*)(ws + 2 * SLOT + 1572864);
  float* bias_perm = (float*)(ws + 2 * SLOT + 1572864 + 524288);
  bf16* qbuf = (bf16*)d_out;                 // q,k scratch inside d_out (dead before proj writes)
  bf16* kbuf = qbuf + 33554432ull;

  static int attr_done = 0;
  if (!attr_done) {
    hipFuncSetAttribute((const void*)k_gemm<0>,
                        hipFuncAttributeMaxDynamicSharedMemorySize, 131072);
    hipFuncSetAttribute((const void*)k_gemm<1>,
                        hipFuncAttributeMaxDynamicSharedMemorySize, 131072);
    hipFuncSetAttribute((const void*)k_attn,
                        hipFuncAttributeMaxDynamicSharedMemorySize, ATTN_LDS);
    attr_done = 1;
  }

  k_conv_x<<<32768, 256, 0, stream>>>((const float4*)x, (ushort4*)slotA);
  k_conv_w<<<dim3(24, 16), 256, 0, stream>>>(Wqkv, bqkv, Wqkv_t, bias_perm, 1536, 1);
  k_conv_w<<<dim3(8, 16), 256, 0, stream>>>(Wproj, nullptr, Wproj_t, nullptr, 512, 0);

  // qkv projection: A=xb, Bt=Wqkv_t -> q,k (d_out), v (slotB)
  k_gemm<0><<<1536, 512, 131072, stream>>>(slotA, Wqkv_t, bias_perm,
                                           qbuf, kbuf, slotB, nullptr, 6);
  // v -> vT (slotA; xb dead)
  k_transpose_v<<<dim3(256, 8, 16), 256, 0, stream>>>(slotB, slotA);
  // attention -> attn_out (slotB; v dead)
  k_attn<<<2048, 512, ATTN_LDS, stream>>>(qbuf, kbuf, slotA, slotB);
  // proj: A=attn_out (slotB), Bt=Wproj_t -> d_out f32 (q,k dead)
  k_gemm<1><<<512, 512, 131072, stream>>>(slotB, Wproj_t, bproj,
                                          nullptr, nullptr, nullptr, (float*)d_out, 2);
}